// Round 14
// baseline (326.415 us; speedup 1.0000x reference)
//
#include <hip/hip_runtime.h>

// SpectralGNNEncoder on MI355X.
// out = (mu, logvar):
//   h1 = relu(Agg1(x@W1) + b1)   (sym-norm scatter-add w/ self loops)
//   g  = mean(Agg2(h1@W2)) + b2 = ((1/N) c^T h1) @ W2 + b2,  c[i]=dinv[i]^2+dinv[i]*S[i]
// Round 24: clean TLP test on k_agg. r13's deep ring was compiler-defeated
// (VGPR stayed 56 -> ring collapsed); the never-run clean experiment is grid
// 1024->2048 with stride-slot mapping UNCHANGED (r4 confounded this with a
// mapping change). k_agg body reverted to the proven r12 4/3-deep ring.
// Everything else byte-identical to r23 (binG hidden gemm, padded CSR,
// foldA + post2).

typedef __bf16 bf16x8 __attribute__((ext_vector_type(8)));
typedef float f32x4 __attribute__((ext_vector_type(4)));
typedef float f32x2 __attribute__((ext_vector_type(2)));
typedef unsigned long long u64;

#define RE   2048   // edges per region (bin block)
#define BSH  8      // bucket = node >> 8 (256 nodes/bucket)
#define BCAP 5120   // CSR slots per bucket (avg 4096, 6-sigma ~4500, +16 tail)
#define NBMX 392    // LDS counter bound (NB = ceil(100000/256) = 391)

__device__ __forceinline__ float bf2f(unsigned short u){
  return __uint_as_float(((unsigned)u) << 16);
}
__device__ __forceinline__ unsigned short f2bf(float f){
  unsigned u = __float_as_uint(f);
  u += 0x7fffu + ((u >> 16) & 1u);   // RNE
  return (unsigned short)(u >> 16);
}
__device__ __forceinline__ __bf16 us2bf(unsigned short u){
  __bf16 b; __builtin_memcpy(&b, &u, 2); return b;
}
__device__ __forceinline__ float ldf(const void* p, int i, int isf32){
  return isf32 ? ((const float*)p)[i] : bf2f(((const unsigned short*)p)[i]);
}
// fma 8 fp8 feats (packed in uint2) into acc[8]
__device__ __forceinline__ void fma8f8(float* acc, float n, uint2 h){
  f32x2 p0 = __builtin_amdgcn_cvt_pk_f32_fp8((int)h.x, false);
  f32x2 p1 = __builtin_amdgcn_cvt_pk_f32_fp8((int)h.x, true);
  f32x2 p2 = __builtin_amdgcn_cvt_pk_f32_fp8((int)h.y, false);
  f32x2 p3 = __builtin_amdgcn_cvt_pk_f32_fp8((int)h.y, true);
  acc[0] = fmaf(n, p0[0], acc[0]);
  acc[1] = fmaf(n, p0[1], acc[1]);
  acc[2] = fmaf(n, p1[0], acc[2]);
  acc[3] = fmaf(n, p1[1], acc[3]);
  acc[4] = fmaf(n, p2[0], acc[4]);
  acc[5] = fmaf(n, p2[1], acc[5]);
  acc[6] = fmaf(n, p3[0], acc[6]);
  acc[7] = fmaf(n, p3[1], acc[7]);
}

// all 256 threads call; scans cnt[0..NB) in place to exclusive-prefix cursors,
// stores counts/offsets to hrow/rrow.
__device__ __forceinline__ void scanBuckets(int* __restrict__ cnt, int* __restrict__ sm,
    int* __restrict__ hrow, int* __restrict__ rrow, int NB, int tid){
  const int K = (NBMX + 255) / 256;   // 2
  int c0 = tid * K;
  int loc = 0;
  #pragma unroll
  for (int i = 0; i < K; ++i){
    int j = c0 + i;
    if (j < NB) loc += cnt[j];
  }
  sm[tid] = loc;
  __syncthreads();
  for (int off = 1; off < 256; off <<= 1){
    int tmp = (tid >= off) ? sm[tid - off] : 0;
    __syncthreads();
    sm[tid] += tmp;
    __syncthreads();
  }
  int running = sm[tid] - loc;
  #pragma unroll
  for (int i = 0; i < K; ++i){
    int j = c0 + i;
    if (j < NB){
      int old = cnt[j];
      hrow[j] = old;
      rrow[j] = running;
      cnt[j] = running;               // becomes scatter cursor
      running += old;
    }
  }
}

// ---------- init: dtype sniff + W1 transpose; block 0: flag, v ----------
__global__ void k_init(const unsigned* __restrict__ xw, int* __restrict__ flag,
                       const void* __restrict__ W1, unsigned short* __restrict__ W1T,
                       float* __restrict__ v){
  __shared__ int s[256];
  int t = threadIdx.x;
  int cnt = 0;
  for (int k = t; k < 4096; k += 256){
    unsigned lo = xw[k] & 0xFFFFu;
    int e = (int)((lo >> 7) & 0xFFu);
    if ((e >= 100 && e <= 141) || (lo & 0x7FFFu) == 0) cnt++;
  }
  s[t] = cnt;
  __syncthreads();
  for (int off = 128; off > 0; off >>= 1){
    if (t < off) s[t] += s[t + off];
    __syncthreads();
  }
  int isf32 = (s[0] < 2458) ? 1 : 0;
  if (blockIdx.x == 0){
    if (t == 0) *flag = isf32;
    if (t < 128) v[t] = 0.0f;
  }
  int gid = blockIdx.x * 256 + t;      // gid = n*128 + k, 64 blocks cover 16384
  int k = gid & 127, n = gid >> 7;
  W1T[gid] = isf32 ? f2bf(((const float*)W1)[k * 128 + n])
                   : ((const unsigned short*)W1)[k * 128 + n];
}

// ---------- binG: blocks [0,NR) = bin (dual-stream LDS bucket sort);
// blocks [NR, NR+nbg) = gemm H = fp8(x@W1) row-major (unprescaled). ----------
__global__ void __launch_bounds__(256) k_binG(const int* __restrict__ src,
    const int* __restrict__ dst, const void* __restrict__ w,
    u64* __restrict__ stagD, u64* __restrict__ stagS,
    int* __restrict__ histD, int* __restrict__ roffD,
    int* __restrict__ histS, int* __restrict__ roffS,
    int E, int NB, int NR,
    const void* __restrict__ xv, const __bf16* __restrict__ wt,
    unsigned char* __restrict__ H, int N, const int* __restrict__ flagp){
  __shared__ int cntD[NBMX];
  __shared__ int cntS[NBMX];
  __shared__ u64 stag[RE];
  __shared__ int sm[256];
  int tid = threadIdx.x;
  if ((int)blockIdx.x >= NR){
    // ---- gemm role ----
    int gb = (int)blockIdx.x - NR;
    int wave = (gb * 256 + tid) >> 6;
    int lane = tid & 63;
    int row16 = wave << 4;
    if (row16 >= N) return;
    int isf32 = *flagp;
    int m = lane & 15, q = lane >> 4;
    bf16x8 a0, a1, a2, a3;
    if (isf32){
      const float* ap = (const float*)xv + (size_t)(row16 + m) * 128 + q * 8;
      #pragma unroll
      for (int j = 0; j < 8; ++j){
        a0[j] = us2bf(f2bf(ap[j +  0]));
        a1[j] = us2bf(f2bf(ap[j + 32]));
        a2[j] = us2bf(f2bf(ap[j + 64]));
        a3[j] = us2bf(f2bf(ap[j + 96]));
      }
    } else {
      const __bf16* ap = (const __bf16*)xv + (size_t)(row16 + m) * 128 + q * 8;
      a0 = *(const bf16x8*)(ap +  0);
      a1 = *(const bf16x8*)(ap + 32);
      a2 = *(const bf16x8*)(ap + 64);
      a3 = *(const bf16x8*)(ap + 96);
    }
    for (int nt = 0; nt < 8; ++nt){
      const __bf16* bp = wt + (size_t)(nt * 16 + m) * 128 + q * 8;
      bf16x8 b0 = *(const bf16x8*)(bp +  0);
      bf16x8 b1 = *(const bf16x8*)(bp + 32);
      bf16x8 b2 = *(const bf16x8*)(bp + 64);
      bf16x8 b3 = *(const bf16x8*)(bp + 96);
      f32x4 acc = {0.f, 0.f, 0.f, 0.f};
      acc = __builtin_amdgcn_mfma_f32_16x16x32_bf16(a0, b0, acc, 0, 0, 0);
      acc = __builtin_amdgcn_mfma_f32_16x16x32_bf16(a1, b1, acc, 0, 0, 0);
      acc = __builtin_amdgcn_mfma_f32_16x16x32_bf16(a2, b2, acc, 0, 0, 0);
      acc = __builtin_amdgcn_mfma_f32_16x16x32_bf16(a3, b3, acc, 0, 0, 0);
      unsigned char* op = H + (size_t)(row16 + q * 4) * 128 + nt * 16 + m;
      op[0]   = (unsigned char)(__builtin_amdgcn_cvt_pk_fp8_f32(acc[0], acc[0], 0, false) & 0xFF);
      op[128] = (unsigned char)(__builtin_amdgcn_cvt_pk_fp8_f32(acc[1], acc[1], 0, false) & 0xFF);
      op[256] = (unsigned char)(__builtin_amdgcn_cvt_pk_fp8_f32(acc[2], acc[2], 0, false) & 0xFF);
      op[384] = (unsigned char)(__builtin_amdgcn_cvt_pk_fp8_f32(acc[3], acc[3], 0, false) & 0xFF);
    }
    return;
  }
  // ---- bin role ----
  int r = blockIdx.x;
  for (int i = tid; i < NB; i += 256){ cntD[i] = 0; cntS[i] = 0; }
  __syncthreads();
  int isf32 = *flagp;
  int e0 = r * RE;
  int en = E - e0; if (en > RE) en = RE;
  u64 rec[8];
  #pragma unroll
  for (int k = 0; k < 8; ++k){
    int o = k * 256 + tid;
    rec[k] = ~0ull;                   // sentinel (impossible: dst < 2^17)
    if (o < en){
      int idx = e0 + o;
      int s_ = src[idx], d_ = dst[idx];
      float wf = ldf(w, idx, isf32);
      int wq = (int)(wf * 32768.0f + 0.5f);
      if (wq > 32767) wq = 32767;
      rec[k] = ((u64)(unsigned)d_ << 32) | ((u64)(unsigned)s_ << 15) | (unsigned)wq;
      atomicAdd(&cntD[d_ >> BSH], 1);
      atomicAdd(&cntS[s_ >> BSH], 1);
    }
  }
  __syncthreads();
  scanBuckets(cntD, sm, histD + (size_t)r * NB, roffD + (size_t)r * NB, NB, tid);
  __syncthreads();
  #pragma unroll
  for (int k = 0; k < 8; ++k){
    if (rec[k] != ~0ull){
      int p = atomicAdd(&cntD[(int)(rec[k] >> 32) >> BSH], 1);
      stag[p] = rec[k];
    }
  }
  __syncthreads();
  u64* opD = stagD + (size_t)r * RE;
  for (int i = tid; i < en; i += 256) opD[i] = stag[i];
  __syncthreads();                    // drain reads of stag before S-scatter
  scanBuckets(cntS, sm, histS + (size_t)r * NB, roffS + (size_t)r * NB, NB, tid);
  __syncthreads();
  #pragma unroll
  for (int k = 0; k < 8; ++k){
    if (rec[k] != ~0ull){
      int d_ = (int)(rec[k] >> 32);
      int s_ = (int)((rec[k] >> 15) & 0x1FFFFu);
      unsigned wq = (unsigned)(rec[k] & 32767u);
      u64 rs = ((u64)(unsigned)s_ << 32) | ((u64)(unsigned)d_ << 15) | wq;
      int p = atomicAdd(&cntS[s_ >> BSH], 1);
      stag[p] = rs;
    }
  }
  __syncthreads();
  u64* opS = stagS + (size_t)r * RE;
  for (int i = tid; i < en; i += 256) opS[i] = stag[i];
}

// ---------- transp4: both (hist,roff) pairs [NR][NB] -> [NB][NR] in one launch ----------
__global__ void __launch_bounds__(256) k_transp4(const int* __restrict__ A,
    const int* __restrict__ B, const int* __restrict__ C, const int* __restrict__ D,
    int* __restrict__ AT, int* __restrict__ BT, int* __restrict__ CT,
    int* __restrict__ DT, int NR, int NB){
  __shared__ int ta[32][33];
  __shared__ int tb[32][33];
  __shared__ int tc[32][33];
  __shared__ int td[32][33];
  int bx = (int)blockIdx.x * 32;      // bucket index base
  int by = (int)blockIdx.y * 32;      // region index base
  int tx = threadIdx.x & 31, ty = threadIdx.x >> 5;   // 32 x 8
  for (int yy = ty; yy < 32; yy += 8){
    int r = by + yy, b = bx + tx;
    int v1 = 0, v2 = 0, v3 = 0, v4 = 0;
    if (r < NR && b < NB){
      size_t o = (size_t)r * NB + b;
      v1 = A[o]; v2 = B[o]; v3 = C[o]; v4 = D[o];
    }
    ta[yy][tx] = v1; tb[yy][tx] = v2; tc[yy][tx] = v3; td[yy][tx] = v4;
  }
  __syncthreads();
  for (int yy = ty; yy < 32; yy += 8){
    int b = bx + yy, r = by + tx;
    if (b < NB && r < NR){
      size_t o = (size_t)b * NR + r;
      AT[o] = ta[tx][yy]; BT[o] = tb[tx][yy];
      CT[o] = tc[tx][yy]; DT[o] = td[tx][yy];
    }
  }
}

// ---------- foldA: dst bucket b: deg/cnt pass over runs -> dinv,
// bucket-local padded-CSR rc = (b*BCAP + prefix, cnt). No global scan. ----------
__global__ void __launch_bounds__(512) k_foldA(const u64* __restrict__ stagD,
    const int* __restrict__ histT, const int* __restrict__ roffT,
    float* __restrict__ dinv, int2* __restrict__ rc, int NR, int N){
  __shared__ unsigned cd[256];
  __shared__ int sm[256];
  int b = blockIdx.x, tid = threadIdx.x;
  int lo = b << BSH;
  int nn = N - lo; if (nn > 256) nn = 256;
  if (tid < 256) cd[tid] = 0u;
  __syncthreads();
  const int* hrow = histT + (size_t)b * NR;
  const int* rrow = roffT + (size_t)b * NR;
  for (int r = tid; r < NR; r += 512){
    int len = hrow[r];
    if (len == 0) continue;
    const u64* rp = stagD + (size_t)r * RE + rrow[r];
    for (int k = 0; k < len; ++k){
      u64 rec = rp[k];
      int dl = (int)(rec >> 32) - lo;
      atomicAdd(&cd[dl], (1u << 20) | (unsigned)((rec & 32767u) >> 2));
    }
  }
  __syncthreads();
  int c = 0;
  if (tid < 256){
    unsigned p = cd[tid];
    float di = rsqrtf(1.0f + (float)(p & 0xFFFFFu) * (1.0f / 8192.0f));
    c = (int)(p >> 20);
    if (tid < nn) dinv[lo + tid] = di;
    sm[tid] = c;
  }
  __syncthreads();
  for (int off = 1; off < 256; off <<= 1){
    int tmp = (tid < 256 && tid >= off) ? sm[tid - off] : 0;
    __syncthreads();
    if (tid < 256) sm[tid] += tmp;
    __syncthreads();
  }
  if (tid < nn) rc[lo + tid] = make_int2(b * BCAP + (sm[tid] - c), c);
}

// ---------- post2: even blocks = CSR fold (original dinv[s]*wq*dinv[d] numerics,
// LDS scatter, coalesced padded write + zero tail); odd = S-role + dc. ----------
__global__ void __launch_bounds__(512) k_post2(const u64* __restrict__ stagD,
    const int* __restrict__ histDT, const int* __restrict__ roffDT,
    const u64* __restrict__ stagS, const int* __restrict__ histST,
    const int* __restrict__ roffST, const float* __restrict__ dinv,
    const int2* __restrict__ rc, unsigned* __restrict__ edges,
    float2* __restrict__ dc, int NR, int N){
  __shared__ unsigned recs[BCAP];     // S-role aliases first 256 floats
  __shared__ int cur[256];
  int b = (int)blockIdx.x >> 1, tid = threadIdx.x;
  int lo = b << BSH;
  int nn = N - lo; if (nn > 256) nn = 256;
  if (blockIdx.x & 1){
    // ---- S role (+ dc) ----
    float* SL = (float*)recs;
    if (tid < 256) SL[tid] = 0.0f;
    __syncthreads();
    const int* hrow = histST + (size_t)b * NR;
    const int* rrow = roffST + (size_t)b * NR;
    for (int r = tid; r < NR; r += 512){
      int len = hrow[r];
      if (len == 0) continue;
      const u64* rp = stagS + (size_t)r * RE + rrow[r];
      for (int k = 0; k < len; ++k){
        u64 rec = rp[k];
        int s_ = (int)(rec >> 32);
        int d_ = (int)((rec >> 15) & 0x1FFFFu);
        float wqf = (float)(rec & 32767u) * (1.0f / 32768.0f);
        atomicAdd(&SL[s_ - lo], wqf * dinv[d_]);
      }
    }
    __syncthreads();
    if (tid < nn){
      int i = lo + tid;
      float di = dinv[i];
      dc[i] = make_float2(di * di, di * di + di * SL[tid]);
    }
    return;
  }
  // ---- CSR role ----
  int tot = 0;
  {
    int2 last = rc[lo + nn - 1];
    tot = (last.x - b * BCAP) + last.y;
  }
  if (tot > BCAP) tot = BCAP;
  if (tid < nn) cur[tid] = rc[lo + tid].x - b * BCAP;
  __syncthreads();
  const int* hrow = histDT + (size_t)b * NR;
  const int* rrow = roffDT + (size_t)b * NR;
  for (int r = tid; r < NR; r += 512){
    int len = hrow[r];
    if (len == 0) continue;
    const u64* rp = stagD + (size_t)r * RE + rrow[r];
    for (int k = 0; k < len; ++k){
      u64 rec = rp[k];
      int d_ = (int)(rec >> 32);
      int s_ = (int)((rec >> 15) & 0x1FFFFu);
      int wq = (int)(rec & 32767u);
      float nrm = dinv[s_] * ((float)wq * (1.0f / 32768.0f)) * dinv[d_];
      int nq = (int)(nrm * 32768.0f + 0.5f);
      if (nq > 32767) nq = 32767;
      int p = atomicAdd(&cur[d_ - lo], 1);
      if (p < BCAP) recs[p] = ((unsigned)s_ << 15) | (unsigned)nq;
    }
  }
  __syncthreads();
  if (tid < 16 && tot + tid < BCAP) recs[tot + tid] = 0u;   // prefetch-safe tail
  __syncthreads();
  int lim = tot + 16; if (lim > BCAP) lim = BCAP;
  unsigned* op = edges + (size_t)b * BCAP;
  for (int i = tid; i < lim; i += 512) op[i] = recs[i];
}

// ---------- k_agg: merged-feature gather (2048 blocks, stride slots).
// slot = 8 lanes; lane q owns features [q*16, q*16+16) as one uint4 of fp8.
// Edge ring 4-deep (e0..e3); H ring 3-deep (h0..h2); next-node prefetch.
// Per-bucket CSR tails zero-padded so prefetch over-reads are benign. ----------
__global__ void __launch_bounds__(256) k_agg(const unsigned char* __restrict__ H,
    const int2* __restrict__ rc, const float2* __restrict__ dc,
    const unsigned* __restrict__ edges, const void* __restrict__ b1,
    float* __restrict__ v, int N, int totslots, const int* __restrict__ flagp){
  __shared__ float vsh[128];
  __shared__ float bsh[128];
  int tid = threadIdx.x;
  int isf32 = *flagp;
  if (tid < 128){ vsh[tid] = 0.0f; bsh[tid] = ldf(b1, tid, isf32); }
  __syncthreads();
  int lane = tid & 63;
  int wv = tid >> 6;                  // wave in block 0..3
  int slot = lane >> 3;               // 0..7 (one destination node per slot)
  int q = lane & 7;                   // feature octet owner: feats q*16..q*16+15
  const unsigned char* Hq = H + q * 16;
  float ax[16];
  #pragma unroll
  for (int j = 0; j < 16; ++j) ax[j] = 0.0f;
  int d = ((int)blockIdx.x * 4 + wv) * 8 + slot;
  int2 rcv = make_int2(0, 0); float2 dcv = make_float2(0.f, 0.f);
  uint4 hs = make_uint4(0u, 0u, 0u, 0u);
  if (d < N){
    rcv = rc[d]; dcv = dc[d];
    hs = *(const uint4*)(Hq + (size_t)d * 128);
  }
  while (d < N){
    int dn = d + totslots;
    int2 rcn = make_int2(0, 0); float2 dcn = make_float2(0.f, 0.f);
    uint4 hsn = make_uint4(0u, 0u, 0u, 0u);
    if (dn < N){                       // next-node prefetch (independent chains)
      rcn = rc[dn]; dcn = dc[dn];
      hsn = *(const uint4*)(Hq + (size_t)dn * 128);
    }
    float acc[16];
    #pragma unroll
    for (int j = 0; j < 16; ++j) acc[j] = 0.0f;
    fma8f8(acc,     dcv.x, make_uint2(hs.x, hs.y));   // self-loop: dinv^2 * H[d]
    fma8f8(acc + 8, dcv.x, make_uint2(hs.z, hs.w));
    int start = rcv.x, len = rcv.y;
    if (len > 0){
      const unsigned* ep = edges + start;
      // tail records (zero) make all over-reads benign: src=0, weight never consumed
      unsigned e0 = ep[0], e1 = ep[1], e2 = ep[2], e3 = ep[3];
      uint4 h0 = *(const uint4*)(Hq + (size_t)(e0 >> 15) * 128);
      uint4 h1 = *(const uint4*)(Hq + (size_t)(e1 >> 15) * 128);
      uint4 h2 = *(const uint4*)(Hq + (size_t)(e2 >> 15) * 128);
      #pragma unroll 2
      for (int k = 0; k < len; ++k){
        unsigned en = ep[k + 4];                                 // 4 ahead
        uint4 hn = *(const uint4*)(Hq + (size_t)(e3 >> 15) * 128);  // e3: 1-iter-old word
        float wn = (float)(e0 & 32767u) * (1.0f / 32768.0f);
        fma8f8(acc,     wn, make_uint2(h0.x, h0.y));
        fma8f8(acc + 8, wn, make_uint2(h0.z, h0.w));
        e0 = e1; e1 = e2; e2 = e3; e3 = en;
        h0 = h1; h1 = h2; h2 = hn;
      }
    }
    #pragma unroll
    for (int j = 0; j < 16; ++j){
      float rj = fmaxf(acc[j] + bsh[q * 16 + j], 0.0f);
      ax[j] = fmaf(dcv.y, rj, ax[j]);
    }
    d = dn; rcv = rcn; dcv = dcn; hs = hsn;
  }
  // cross-slot reduce (slot = lane bits 3..5), once per wave
  #pragma unroll
  for (int j = 0; j < 16; ++j){
    ax[j] += __shfl_xor(ax[j], 8);
    ax[j] += __shfl_xor(ax[j], 16);
    ax[j] += __shfl_xor(ax[j], 32);
  }
  if (slot == 0){
    #pragma unroll
    for (int j = 0; j < 16; ++j) atomicAdd(&vsh[q * 16 + j], ax[j]);
  }
  __syncthreads();
  if (tid < 128) atomicAdd(&v[tid], vsh[tid]);
}

// ---------- tiny head ----------
__global__ void __launch_bounds__(128) k_head(const float* __restrict__ v,
    const void* __restrict__ W2, const void* __restrict__ b2,
    const void* __restrict__ Wmu, const void* __restrict__ bmu,
    const void* __restrict__ Wlv, const void* __restrict__ blv,
    void* __restrict__ outv, float invN, const int* __restrict__ flagp){
  __shared__ float gsh[128];
  __shared__ float tsh[128];
  int t = threadIdx.x;
  int isf32 = *flagp;
  gsh[t] = v[t] * invN;
  __syncthreads();
  float acc = ldf(b2, t, isf32);
  for (int k = 0; k < 128; ++k) acc = fmaf(gsh[k], ldf(W2, k * 128 + t, isf32), acc);
  tsh[t] = acc;
  __syncthreads();
  int j = t & 63;
  const void* Wp = (t < 64) ? Wmu : Wlv;
  float o = ldf((t < 64) ? bmu : blv, j, isf32);
  for (int k = 0; k < 128; ++k) o = fmaf(tsh[k], ldf(Wp, k * 64 + j, isf32), o);
  if (isf32) ((float*)outv)[t] = o;
  else       ((unsigned short*)outv)[t] = f2bf(o);
}

extern "C" void kernel_launch(void* const* d_in, const int* in_sizes, int n_in,
                              void* d_out, int out_size, void* d_ws, size_t ws_size,
                              hipStream_t stream) {
  const void* x   = d_in[0];
  const int*  ei  = (const int*)d_in[1];
  const void* w   = d_in[2];
  const void* W1  = d_in[3];
  const void* b1  = d_in[4];
  const void* W2  = d_in[5];
  const void* b2  = d_in[6];
  const void* Wmu = d_in[7];
  const void* bmu = d_in[8];
  const void* Wlv = d_in[9];
  const void* blv = d_in[10];

  const int N = in_sizes[0] / 128;     // 100000
  const int E = in_sizes[2];           // 1600000
  const int* src = ei;
  const int* dst = ei + E;

  char* wsb = (char*)d_ws;
  size_t off = 0;
  auto alloc = [&](size_t bytes) -> void* {
    off = (off + 255) & ~(size_t)255;
    void* p = wsb + off;
    off += bytes;
    return p;
  };
  const int NR  = (E + RE - 1) / RE;    // 782 regions
  const int NB  = (N + 255) >> BSH;     // 391 buckets
  int*   flag     = (int*)  alloc(16);
  float* dinv     = (float*)alloc((size_t)N * 4 + 16);
  float2* dc      = (float2*)alloc((size_t)N * 8);
  int2*   rc      = (int2*) alloc((size_t)N * 8);
  float* v        = (float*)alloc(128 * 4);
  unsigned short* W1T = (unsigned short*)alloc(128 * 128 * 2);
  u64*   stagD    = (u64*)  alloc((size_t)NR * RE * 8);      // 12.8 MB
  u64*   stagS    = (u64*)  alloc((size_t)NR * RE * 8);      // 12.8 MB
  int*   histD    = (int*)  alloc((size_t)NR * NB * 4);      // 1.22 MB each
  int*   roffD    = (int*)  alloc((size_t)NR * NB * 4);
  int*   histS    = (int*)  alloc((size_t)NR * NB * 4);
  int*   roffS    = (int*)  alloc((size_t)NR * NB * 4);
  int*   histDT   = (int*)  alloc((size_t)NB * NR * 4);
  int*   roffDT   = (int*)  alloc((size_t)NB * NR * 4);
  int*   histST   = (int*)  alloc((size_t)NB * NR * 4);
  int*   roffST   = (int*)  alloc((size_t)NB * NR * 4);
  unsigned* edges = (unsigned*)alloc((size_t)NB * BCAP * 4 + 64);  // padded CSR
  unsigned char* H = (unsigned char*)alloc((size_t)N * 128);
  (void)ws_size; (void)n_in; (void)out_size;

  const int nwaves = (N + 15) / 16;
  const int nb_g = (nwaves + 3) / 4;   // 1563 gemm blocks

  k_init<<<64, 256, 0, stream>>>((const unsigned*)x, flag, W1, W1T, v);
  k_binG<<<NR + nb_g, 256, 0, stream>>>(src, dst, w, stagD, stagS,
                                        histD, roffD, histS, roffS, E, NB, NR,
                                        x, (const __bf16*)W1T, H, N, flag);
  dim3 tg((NB + 31) / 32, (NR + 31) / 32);
  k_transp4<<<tg, 256, 0, stream>>>(histD, roffD, histS, roffS,
                                    histDT, roffDT, histST, roffST, NR, NB);
  k_foldA<<<NB, 512, 0, stream>>>(stagD, histDT, roffDT, dinv, rc, NR, N);
  k_post2<<<2 * NB, 512, 0, stream>>>(stagD, histDT, roffDT, stagS, histST,
                                      roffST, dinv, rc, edges, dc, NR, N);
  const int nb_agg = 2048;             // clean TLP test: 8192 waves, stride slots
  k_agg<<<nb_agg, 256, 0, stream>>>(H, rc, dc, edges, b1, v, N, nb_agg * 32, flag);
  k_head<<<1, 128, 0, stream>>>(v, W2, b2, Wmu, bmu, Wlv, blv,
                                d_out, 1.0f / (float)N, flag);
}

// Round 15
// 301.886 us; speedup vs baseline: 1.0813x; 1.0813x over previous
//
#include <hip/hip_runtime.h>

// SpectralGNNEncoder on MI355X.
// out = (mu, logvar):
//   h1 = relu(Agg1(x@W1) + b1)   (sym-norm scatter-add w/ self loops)
//   g  = mean(Agg2(h1@W2)) + b2 = ((1/N) c^T h1) @ W2 + b2,  c[i]=dinv[i]^2+dinv[i]*S[i]
// Round 25: k_agg closed (ILP null r13, TLP negative r14 -> 1024 blocks is the
// structural optimum, revert). Preprocessing lever: RE 2048->4096 (NR 782->391):
// staging runs avg 5.2->10.5 records -> line efficiency ~55%->~75% on the
// scattered foldA/post2 staging reads; hist/roff + transpose halve.
// Bin role: 16 edges/thread (rec[16]), 36KB LDS. All else byte-identical.

typedef __bf16 bf16x8 __attribute__((ext_vector_type(8)));
typedef float f32x4 __attribute__((ext_vector_type(4)));
typedef float f32x2 __attribute__((ext_vector_type(2)));
typedef unsigned long long u64;

#define RE   4096   // edges per region (bin block)
#define BSH  8      // bucket = node >> 8 (256 nodes/bucket)
#define BCAP 5120   // CSR slots per bucket (avg 4096, 6-sigma ~4500, +16 tail)
#define NBMX 392    // LDS counter bound (NB = ceil(100000/256) = 391)

__device__ __forceinline__ float bf2f(unsigned short u){
  return __uint_as_float(((unsigned)u) << 16);
}
__device__ __forceinline__ unsigned short f2bf(float f){
  unsigned u = __float_as_uint(f);
  u += 0x7fffu + ((u >> 16) & 1u);   // RNE
  return (unsigned short)(u >> 16);
}
__device__ __forceinline__ __bf16 us2bf(unsigned short u){
  __bf16 b; __builtin_memcpy(&b, &u, 2); return b;
}
__device__ __forceinline__ float ldf(const void* p, int i, int isf32){
  return isf32 ? ((const float*)p)[i] : bf2f(((const unsigned short*)p)[i]);
}
// fma 8 fp8 feats (packed in uint2) into acc[8]
__device__ __forceinline__ void fma8f8(float* acc, float n, uint2 h){
  f32x2 p0 = __builtin_amdgcn_cvt_pk_f32_fp8((int)h.x, false);
  f32x2 p1 = __builtin_amdgcn_cvt_pk_f32_fp8((int)h.x, true);
  f32x2 p2 = __builtin_amdgcn_cvt_pk_f32_fp8((int)h.y, false);
  f32x2 p3 = __builtin_amdgcn_cvt_pk_f32_fp8((int)h.y, true);
  acc[0] = fmaf(n, p0[0], acc[0]);
  acc[1] = fmaf(n, p0[1], acc[1]);
  acc[2] = fmaf(n, p1[0], acc[2]);
  acc[3] = fmaf(n, p1[1], acc[3]);
  acc[4] = fmaf(n, p2[0], acc[4]);
  acc[5] = fmaf(n, p2[1], acc[5]);
  acc[6] = fmaf(n, p3[0], acc[6]);
  acc[7] = fmaf(n, p3[1], acc[7]);
}

// all 256 threads call; scans cnt[0..NB) in place to exclusive-prefix cursors,
// stores counts/offsets to hrow/rrow.
__device__ __forceinline__ void scanBuckets(int* __restrict__ cnt, int* __restrict__ sm,
    int* __restrict__ hrow, int* __restrict__ rrow, int NB, int tid){
  const int K = (NBMX + 255) / 256;   // 2
  int c0 = tid * K;
  int loc = 0;
  #pragma unroll
  for (int i = 0; i < K; ++i){
    int j = c0 + i;
    if (j < NB) loc += cnt[j];
  }
  sm[tid] = loc;
  __syncthreads();
  for (int off = 1; off < 256; off <<= 1){
    int tmp = (tid >= off) ? sm[tid - off] : 0;
    __syncthreads();
    sm[tid] += tmp;
    __syncthreads();
  }
  int running = sm[tid] - loc;
  #pragma unroll
  for (int i = 0; i < K; ++i){
    int j = c0 + i;
    if (j < NB){
      int old = cnt[j];
      hrow[j] = old;
      rrow[j] = running;
      cnt[j] = running;               // becomes scatter cursor
      running += old;
    }
  }
}

// ---------- init: dtype sniff + W1 transpose; block 0: flag, v ----------
__global__ void k_init(const unsigned* __restrict__ xw, int* __restrict__ flag,
                       const void* __restrict__ W1, unsigned short* __restrict__ W1T,
                       float* __restrict__ v){
  __shared__ int s[256];
  int t = threadIdx.x;
  int cnt = 0;
  for (int k = t; k < 4096; k += 256){
    unsigned lo = xw[k] & 0xFFFFu;
    int e = (int)((lo >> 7) & 0xFFu);
    if ((e >= 100 && e <= 141) || (lo & 0x7FFFu) == 0) cnt++;
  }
  s[t] = cnt;
  __syncthreads();
  for (int off = 128; off > 0; off >>= 1){
    if (t < off) s[t] += s[t + off];
    __syncthreads();
  }
  int isf32 = (s[0] < 2458) ? 1 : 0;
  if (blockIdx.x == 0){
    if (t == 0) *flag = isf32;
    if (t < 128) v[t] = 0.0f;
  }
  int gid = blockIdx.x * 256 + t;      // gid = n*128 + k, 64 blocks cover 16384
  int k = gid & 127, n = gid >> 7;
  W1T[gid] = isf32 ? f2bf(((const float*)W1)[k * 128 + n])
                   : ((const unsigned short*)W1)[k * 128 + n];
}

// ---------- binG: blocks [0,NR) = bin (dual-stream LDS bucket sort, 16 e/thr);
// blocks [NR, NR+nbg) = gemm H = fp8(x@W1) row-major (unprescaled). ----------
__global__ void __launch_bounds__(256) k_binG(const int* __restrict__ src,
    const int* __restrict__ dst, const void* __restrict__ w,
    u64* __restrict__ stagD, u64* __restrict__ stagS,
    int* __restrict__ histD, int* __restrict__ roffD,
    int* __restrict__ histS, int* __restrict__ roffS,
    int E, int NB, int NR,
    const void* __restrict__ xv, const __bf16* __restrict__ wt,
    unsigned char* __restrict__ H, int N, const int* __restrict__ flagp){
  __shared__ int cntD[NBMX];
  __shared__ int cntS[NBMX];
  __shared__ u64 stag[RE];
  __shared__ int sm[256];
  int tid = threadIdx.x;
  if ((int)blockIdx.x >= NR){
    // ---- gemm role ----
    int gb = (int)blockIdx.x - NR;
    int wave = (gb * 256 + tid) >> 6;
    int lane = tid & 63;
    int row16 = wave << 4;
    if (row16 >= N) return;
    int isf32 = *flagp;
    int m = lane & 15, q = lane >> 4;
    bf16x8 a0, a1, a2, a3;
    if (isf32){
      const float* ap = (const float*)xv + (size_t)(row16 + m) * 128 + q * 8;
      #pragma unroll
      for (int j = 0; j < 8; ++j){
        a0[j] = us2bf(f2bf(ap[j +  0]));
        a1[j] = us2bf(f2bf(ap[j + 32]));
        a2[j] = us2bf(f2bf(ap[j + 64]));
        a3[j] = us2bf(f2bf(ap[j + 96]));
      }
    } else {
      const __bf16* ap = (const __bf16*)xv + (size_t)(row16 + m) * 128 + q * 8;
      a0 = *(const bf16x8*)(ap +  0);
      a1 = *(const bf16x8*)(ap + 32);
      a2 = *(const bf16x8*)(ap + 64);
      a3 = *(const bf16x8*)(ap + 96);
    }
    for (int nt = 0; nt < 8; ++nt){
      const __bf16* bp = wt + (size_t)(nt * 16 + m) * 128 + q * 8;
      bf16x8 b0 = *(const bf16x8*)(bp +  0);
      bf16x8 b1 = *(const bf16x8*)(bp + 32);
      bf16x8 b2 = *(const bf16x8*)(bp + 64);
      bf16x8 b3 = *(const bf16x8*)(bp + 96);
      f32x4 acc = {0.f, 0.f, 0.f, 0.f};
      acc = __builtin_amdgcn_mfma_f32_16x16x32_bf16(a0, b0, acc, 0, 0, 0);
      acc = __builtin_amdgcn_mfma_f32_16x16x32_bf16(a1, b1, acc, 0, 0, 0);
      acc = __builtin_amdgcn_mfma_f32_16x16x32_bf16(a2, b2, acc, 0, 0, 0);
      acc = __builtin_amdgcn_mfma_f32_16x16x32_bf16(a3, b3, acc, 0, 0, 0);
      unsigned char* op = H + (size_t)(row16 + q * 4) * 128 + nt * 16 + m;
      op[0]   = (unsigned char)(__builtin_amdgcn_cvt_pk_fp8_f32(acc[0], acc[0], 0, false) & 0xFF);
      op[128] = (unsigned char)(__builtin_amdgcn_cvt_pk_fp8_f32(acc[1], acc[1], 0, false) & 0xFF);
      op[256] = (unsigned char)(__builtin_amdgcn_cvt_pk_fp8_f32(acc[2], acc[2], 0, false) & 0xFF);
      op[384] = (unsigned char)(__builtin_amdgcn_cvt_pk_fp8_f32(acc[3], acc[3], 0, false) & 0xFF);
    }
    return;
  }
  // ---- bin role ----
  int r = blockIdx.x;
  for (int i = tid; i < NB; i += 256){ cntD[i] = 0; cntS[i] = 0; }
  __syncthreads();
  int isf32 = *flagp;
  int e0 = r * RE;
  int en = E - e0; if (en > RE) en = RE;
  u64 rec[16];
  #pragma unroll
  for (int k = 0; k < 16; ++k){
    int o = k * 256 + tid;
    rec[k] = ~0ull;                   // sentinel (impossible: dst < 2^17)
    if (o < en){
      int idx = e0 + o;
      int s_ = src[idx], d_ = dst[idx];
      float wf = ldf(w, idx, isf32);
      int wq = (int)(wf * 32768.0f + 0.5f);
      if (wq > 32767) wq = 32767;
      rec[k] = ((u64)(unsigned)d_ << 32) | ((u64)(unsigned)s_ << 15) | (unsigned)wq;
      atomicAdd(&cntD[d_ >> BSH], 1);
      atomicAdd(&cntS[s_ >> BSH], 1);
    }
  }
  __syncthreads();
  scanBuckets(cntD, sm, histD + (size_t)r * NB, roffD + (size_t)r * NB, NB, tid);
  __syncthreads();
  #pragma unroll
  for (int k = 0; k < 16; ++k){
    if (rec[k] != ~0ull){
      int p = atomicAdd(&cntD[(int)(rec[k] >> 32) >> BSH], 1);
      stag[p] = rec[k];
    }
  }
  __syncthreads();
  u64* opD = stagD + (size_t)r * RE;
  for (int i = tid; i < en; i += 256) opD[i] = stag[i];
  __syncthreads();                    // drain reads of stag before S-scatter
  scanBuckets(cntS, sm, histS + (size_t)r * NB, roffS + (size_t)r * NB, NB, tid);
  __syncthreads();
  #pragma unroll
  for (int k = 0; k < 16; ++k){
    if (rec[k] != ~0ull){
      int d_ = (int)(rec[k] >> 32);
      int s_ = (int)((rec[k] >> 15) & 0x1FFFFu);
      unsigned wq = (unsigned)(rec[k] & 32767u);
      u64 rs = ((u64)(unsigned)s_ << 32) | ((u64)(unsigned)d_ << 15) | wq;
      int p = atomicAdd(&cntS[s_ >> BSH], 1);
      stag[p] = rs;
    }
  }
  __syncthreads();
  u64* opS = stagS + (size_t)r * RE;
  for (int i = tid; i < en; i += 256) opS[i] = stag[i];
}

// ---------- transp4: both (hist,roff) pairs [NR][NB] -> [NB][NR] in one launch ----------
__global__ void __launch_bounds__(256) k_transp4(const int* __restrict__ A,
    const int* __restrict__ B, const int* __restrict__ C, const int* __restrict__ D,
    int* __restrict__ AT, int* __restrict__ BT, int* __restrict__ CT,
    int* __restrict__ DT, int NR, int NB){
  __shared__ int ta[32][33];
  __shared__ int tb[32][33];
  __shared__ int tc[32][33];
  __shared__ int td[32][33];
  int bx = (int)blockIdx.x * 32;      // bucket index base
  int by = (int)blockIdx.y * 32;      // region index base
  int tx = threadIdx.x & 31, ty = threadIdx.x >> 5;   // 32 x 8
  for (int yy = ty; yy < 32; yy += 8){
    int r = by + yy, b = bx + tx;
    int v1 = 0, v2 = 0, v3 = 0, v4 = 0;
    if (r < NR && b < NB){
      size_t o = (size_t)r * NB + b;
      v1 = A[o]; v2 = B[o]; v3 = C[o]; v4 = D[o];
    }
    ta[yy][tx] = v1; tb[yy][tx] = v2; tc[yy][tx] = v3; td[yy][tx] = v4;
  }
  __syncthreads();
  for (int yy = ty; yy < 32; yy += 8){
    int b = bx + yy, r = by + tx;
    if (b < NB && r < NR){
      size_t o = (size_t)b * NR + r;
      AT[o] = ta[tx][yy]; BT[o] = tb[tx][yy];
      CT[o] = tc[tx][yy]; DT[o] = td[tx][yy];
    }
  }
}

// ---------- foldA: dst bucket b: deg/cnt pass over runs -> dinv,
// bucket-local padded-CSR rc = (b*BCAP + prefix, cnt). No global scan. ----------
__global__ void __launch_bounds__(512) k_foldA(const u64* __restrict__ stagD,
    const int* __restrict__ histT, const int* __restrict__ roffT,
    float* __restrict__ dinv, int2* __restrict__ rc, int NR, int N){
  __shared__ unsigned cd[256];
  __shared__ int sm[256];
  int b = blockIdx.x, tid = threadIdx.x;
  int lo = b << BSH;
  int nn = N - lo; if (nn > 256) nn = 256;
  if (tid < 256) cd[tid] = 0u;
  __syncthreads();
  const int* hrow = histT + (size_t)b * NR;
  const int* rrow = roffT + (size_t)b * NR;
  for (int r = tid; r < NR; r += 512){
    int len = hrow[r];
    if (len == 0) continue;
    const u64* rp = stagD + (size_t)r * RE + rrow[r];
    for (int k = 0; k < len; ++k){
      u64 rec = rp[k];
      int dl = (int)(rec >> 32) - lo;
      atomicAdd(&cd[dl], (1u << 20) | (unsigned)((rec & 32767u) >> 2));
    }
  }
  __syncthreads();
  int c = 0;
  if (tid < 256){
    unsigned p = cd[tid];
    float di = rsqrtf(1.0f + (float)(p & 0xFFFFFu) * (1.0f / 8192.0f));
    c = (int)(p >> 20);
    if (tid < nn) dinv[lo + tid] = di;
    sm[tid] = c;
  }
  __syncthreads();
  for (int off = 1; off < 256; off <<= 1){
    int tmp = (tid < 256 && tid >= off) ? sm[tid - off] : 0;
    __syncthreads();
    if (tid < 256) sm[tid] += tmp;
    __syncthreads();
  }
  if (tid < nn) rc[lo + tid] = make_int2(b * BCAP + (sm[tid] - c), c);
}

// ---------- post2: even blocks = CSR fold (original dinv[s]*wq*dinv[d] numerics,
// LDS scatter, coalesced padded write + zero tail); odd = S-role + dc. ----------
__global__ void __launch_bounds__(512) k_post2(const u64* __restrict__ stagD,
    const int* __restrict__ histDT, const int* __restrict__ roffDT,
    const u64* __restrict__ stagS, const int* __restrict__ histST,
    const int* __restrict__ roffST, const float* __restrict__ dinv,
    const int2* __restrict__ rc, unsigned* __restrict__ edges,
    float2* __restrict__ dc, int NR, int N){
  __shared__ unsigned recs[BCAP];     // S-role aliases first 256 floats
  __shared__ int cur[256];
  int b = (int)blockIdx.x >> 1, tid = threadIdx.x;
  int lo = b << BSH;
  int nn = N - lo; if (nn > 256) nn = 256;
  if (blockIdx.x & 1){
    // ---- S role (+ dc) ----
    float* SL = (float*)recs;
    if (tid < 256) SL[tid] = 0.0f;
    __syncthreads();
    const int* hrow = histST + (size_t)b * NR;
    const int* rrow = roffST + (size_t)b * NR;
    for (int r = tid; r < NR; r += 512){
      int len = hrow[r];
      if (len == 0) continue;
      const u64* rp = stagS + (size_t)r * RE + rrow[r];
      for (int k = 0; k < len; ++k){
        u64 rec = rp[k];
        int s_ = (int)(rec >> 32);
        int d_ = (int)((rec >> 15) & 0x1FFFFu);
        float wqf = (float)(rec & 32767u) * (1.0f / 32768.0f);
        atomicAdd(&SL[s_ - lo], wqf * dinv[d_]);
      }
    }
    __syncthreads();
    if (tid < nn){
      int i = lo + tid;
      float di = dinv[i];
      dc[i] = make_float2(di * di, di * di + di * SL[tid]);
    }
    return;
  }
  // ---- CSR role ----
  int tot = 0;
  {
    int2 last = rc[lo + nn - 1];
    tot = (last.x - b * BCAP) + last.y;
  }
  if (tot > BCAP) tot = BCAP;
  if (tid < nn) cur[tid] = rc[lo + tid].x - b * BCAP;
  __syncthreads();
  const int* hrow = histDT + (size_t)b * NR;
  const int* rrow = roffDT + (size_t)b * NR;
  for (int r = tid; r < NR; r += 512){
    int len = hrow[r];
    if (len == 0) continue;
    const u64* rp = stagD + (size_t)r * RE + rrow[r];
    for (int k = 0; k < len; ++k){
      u64 rec = rp[k];
      int d_ = (int)(rec >> 32);
      int s_ = (int)((rec >> 15) & 0x1FFFFu);
      int wq = (int)(rec & 32767u);
      float nrm = dinv[s_] * ((float)wq * (1.0f / 32768.0f)) * dinv[d_];
      int nq = (int)(nrm * 32768.0f + 0.5f);
      if (nq > 32767) nq = 32767;
      int p = atomicAdd(&cur[d_ - lo], 1);
      if (p < BCAP) recs[p] = ((unsigned)s_ << 15) | (unsigned)nq;
    }
  }
  __syncthreads();
  if (tid < 16 && tot + tid < BCAP) recs[tot + tid] = 0u;   // prefetch-safe tail
  __syncthreads();
  int lim = tot + 16; if (lim > BCAP) lim = BCAP;
  unsigned* op = edges + (size_t)b * BCAP;
  for (int i = tid; i < lim; i += 512) op[i] = recs[i];
}

// ---------- k_agg: merged-feature gather (1024 blocks, stride slots).
// slot = 8 lanes; lane q owns features [q*16, q*16+16) as one uint4 of fp8.
// Edge ring 4-deep (e0..e3); H ring 3-deep (h0..h2); next-node prefetch.
// Per-bucket CSR tails zero-padded so prefetch over-reads are benign. ----------
__global__ void __launch_bounds__(256) k_agg(const unsigned char* __restrict__ H,
    const int2* __restrict__ rc, const float2* __restrict__ dc,
    const unsigned* __restrict__ edges, const void* __restrict__ b1,
    float* __restrict__ v, int N, int totslots, const int* __restrict__ flagp){
  __shared__ float vsh[128];
  __shared__ float bsh[128];
  int tid = threadIdx.x;
  int isf32 = *flagp;
  if (tid < 128){ vsh[tid] = 0.0f; bsh[tid] = ldf(b1, tid, isf32); }
  __syncthreads();
  int lane = tid & 63;
  int wv = tid >> 6;                  // wave in block 0..3
  int slot = lane >> 3;               // 0..7 (one destination node per slot)
  int q = lane & 7;                   // feature octet owner: feats q*16..q*16+15
  const unsigned char* Hq = H + q * 16;
  float ax[16];
  #pragma unroll
  for (int j = 0; j < 16; ++j) ax[j] = 0.0f;
  int d = ((int)blockIdx.x * 4 + wv) * 8 + slot;
  int2 rcv = make_int2(0, 0); float2 dcv = make_float2(0.f, 0.f);
  uint4 hs = make_uint4(0u, 0u, 0u, 0u);
  if (d < N){
    rcv = rc[d]; dcv = dc[d];
    hs = *(const uint4*)(Hq + (size_t)d * 128);
  }
  while (d < N){
    int dn = d + totslots;
    int2 rcn = make_int2(0, 0); float2 dcn = make_float2(0.f, 0.f);
    uint4 hsn = make_uint4(0u, 0u, 0u, 0u);
    if (dn < N){                       // next-node prefetch (independent chains)
      rcn = rc[dn]; dcn = dc[dn];
      hsn = *(const uint4*)(Hq + (size_t)dn * 128);
    }
    float acc[16];
    #pragma unroll
    for (int j = 0; j < 16; ++j) acc[j] = 0.0f;
    fma8f8(acc,     dcv.x, make_uint2(hs.x, hs.y));   // self-loop: dinv^2 * H[d]
    fma8f8(acc + 8, dcv.x, make_uint2(hs.z, hs.w));
    int start = rcv.x, len = rcv.y;
    if (len > 0){
      const unsigned* ep = edges + start;
      // tail records (zero) make all over-reads benign: src=0, weight never consumed
      unsigned e0 = ep[0], e1 = ep[1], e2 = ep[2], e3 = ep[3];
      uint4 h0 = *(const uint4*)(Hq + (size_t)(e0 >> 15) * 128);
      uint4 h1 = *(const uint4*)(Hq + (size_t)(e1 >> 15) * 128);
      uint4 h2 = *(const uint4*)(Hq + (size_t)(e2 >> 15) * 128);
      #pragma unroll 2
      for (int k = 0; k < len; ++k){
        unsigned en = ep[k + 4];                                 // 4 ahead
        uint4 hn = *(const uint4*)(Hq + (size_t)(e3 >> 15) * 128);  // e3: 1-iter-old word
        float wn = (float)(e0 & 32767u) * (1.0f / 32768.0f);
        fma8f8(acc,     wn, make_uint2(h0.x, h0.y));
        fma8f8(acc + 8, wn, make_uint2(h0.z, h0.w));
        e0 = e1; e1 = e2; e2 = e3; e3 = en;
        h0 = h1; h1 = h2; h2 = hn;
      }
    }
    #pragma unroll
    for (int j = 0; j < 16; ++j){
      float rj = fmaxf(acc[j] + bsh[q * 16 + j], 0.0f);
      ax[j] = fmaf(dcv.y, rj, ax[j]);
    }
    d = dn; rcv = rcn; dcv = dcn; hs = hsn;
  }
  // cross-slot reduce (slot = lane bits 3..5), once per wave
  #pragma unroll
  for (int j = 0; j < 16; ++j){
    ax[j] += __shfl_xor(ax[j], 8);
    ax[j] += __shfl_xor(ax[j], 16);
    ax[j] += __shfl_xor(ax[j], 32);
  }
  if (slot == 0){
    #pragma unroll
    for (int j = 0; j < 16; ++j) atomicAdd(&vsh[q * 16 + j], ax[j]);
  }
  __syncthreads();
  if (tid < 128) atomicAdd(&v[tid], vsh[tid]);
}

// ---------- tiny head ----------
__global__ void __launch_bounds__(128) k_head(const float* __restrict__ v,
    const void* __restrict__ W2, const void* __restrict__ b2,
    const void* __restrict__ Wmu, const void* __restrict__ bmu,
    const void* __restrict__ Wlv, const void* __restrict__ blv,
    void* __restrict__ outv, float invN, const int* __restrict__ flagp){
  __shared__ float gsh[128];
  __shared__ float tsh[128];
  int t = threadIdx.x;
  int isf32 = *flagp;
  gsh[t] = v[t] * invN;
  __syncthreads();
  float acc = ldf(b2, t, isf32);
  for (int k = 0; k < 128; ++k) acc = fmaf(gsh[k], ldf(W2, k * 128 + t, isf32), acc);
  tsh[t] = acc;
  __syncthreads();
  int j = t & 63;
  const void* Wp = (t < 64) ? Wmu : Wlv;
  float o = ldf((t < 64) ? bmu : blv, j, isf32);
  for (int k = 0; k < 128; ++k) o = fmaf(tsh[k], ldf(Wp, k * 64 + j, isf32), o);
  if (isf32) ((float*)outv)[t] = o;
  else       ((unsigned short*)outv)[t] = f2bf(o);
}

extern "C" void kernel_launch(void* const* d_in, const int* in_sizes, int n_in,
                              void* d_out, int out_size, void* d_ws, size_t ws_size,
                              hipStream_t stream) {
  const void* x   = d_in[0];
  const int*  ei  = (const int*)d_in[1];
  const void* w   = d_in[2];
  const void* W1  = d_in[3];
  const void* b1  = d_in[4];
  const void* W2  = d_in[5];
  const void* b2  = d_in[6];
  const void* Wmu = d_in[7];
  const void* bmu = d_in[8];
  const void* Wlv = d_in[9];
  const void* blv = d_in[10];

  const int N = in_sizes[0] / 128;     // 100000
  const int E = in_sizes[2];           // 1600000
  const int* src = ei;
  const int* dst = ei + E;

  char* wsb = (char*)d_ws;
  size_t off = 0;
  auto alloc = [&](size_t bytes) -> void* {
    off = (off + 255) & ~(size_t)255;
    void* p = wsb + off;
    off += bytes;
    return p;
  };
  const int NR  = (E + RE - 1) / RE;    // 391 regions
  const int NB  = (N + 255) >> BSH;     // 391 buckets
  int*   flag     = (int*)  alloc(16);
  float* dinv     = (float*)alloc((size_t)N * 4 + 16);
  float2* dc      = (float2*)alloc((size_t)N * 8);
  int2*   rc      = (int2*) alloc((size_t)N * 8);
  float* v        = (float*)alloc(128 * 4);
  unsigned short* W1T = (unsigned short*)alloc(128 * 128 * 2);
  u64*   stagD    = (u64*)  alloc((size_t)NR * RE * 8);      // 12.8 MB
  u64*   stagS    = (u64*)  alloc((size_t)NR * RE * 8);      // 12.8 MB
  int*   histD    = (int*)  alloc((size_t)NR * NB * 4);      // 0.61 MB each
  int*   roffD    = (int*)  alloc((size_t)NR * NB * 4);
  int*   histS    = (int*)  alloc((size_t)NR * NB * 4);
  int*   roffS    = (int*)  alloc((size_t)NR * NB * 4);
  int*   histDT   = (int*)  alloc((size_t)NB * NR * 4);
  int*   roffDT   = (int*)  alloc((size_t)NB * NR * 4);
  int*   histST   = (int*)  alloc((size_t)NB * NR * 4);
  int*   roffST   = (int*)  alloc((size_t)NB * NR * 4);
  unsigned* edges = (unsigned*)alloc((size_t)NB * BCAP * 4 + 64);  // padded CSR
  unsigned char* H = (unsigned char*)alloc((size_t)N * 128);
  (void)ws_size; (void)n_in; (void)out_size;

  const int nwaves = (N + 15) / 16;
  const int nb_g = (nwaves + 3) / 4;   // 1563 gemm blocks

  k_init<<<64, 256, 0, stream>>>((const unsigned*)x, flag, W1, W1T, v);
  k_binG<<<NR + nb_g, 256, 0, stream>>>(src, dst, w, stagD, stagS,
                                        histD, roffD, histS, roffS, E, NB, NR,
                                        x, (const __bf16*)W1T, H, N, flag);
  dim3 tg((NB + 31) / 32, (NR + 31) / 32);
  k_transp4<<<tg, 256, 0, stream>>>(histD, roffD, histS, roffS,
                                    histDT, roffDT, histST, roffST, NR, NB);
  k_foldA<<<NB, 512, 0, stream>>>(stagD, histDT, roffDT, dinv, rc, NR, N);
  k_post2<<<2 * NB, 512, 0, stream>>>(stagD, histDT, roffDT, stagS, histST,
                                      roffST, dinv, rc, edges, dc, NR, N);
  const int nb_agg = 1024;             // proven optimum: 4096 waves, stride slots
  k_agg<<<nb_agg, 256, 0, stream>>>(H, rc, dc, edges, b1, v, N, nb_agg * 32, flag);
  k_head<<<1, 128, 0, stream>>>(v, W2, b2, Wmu, bmu, Wlv, blv,
                                d_out, 1.0f / (float)N, flag);
}